// Round 4
// baseline (449.494 us; speedup 1.0000x reference)
//
#include <hip/hip_runtime.h>
#include <hip/hip_bf16.h>

typedef unsigned short u16;
typedef __bf16 bf16x8 __attribute__((ext_vector_type(8)));
typedef float f32x4 __attribute__((ext_vector_type(4)));
typedef unsigned int u32x4 __attribute__((ext_vector_type(4)));

#define SCALE_F 0.17677669529663687f

__device__ __forceinline__ u16 f2b(float f) {
    unsigned u = __builtin_bit_cast(unsigned, f);
    u = (u + 0x7fffu + ((u >> 16) & 1u)) >> 16;   // RNE, no NaN in our data
    return (u16)u;
}

__device__ __forceinline__ f32x4 mfma16(bf16x8 a, bf16x8 b, f32x4 c) {
    return __builtin_amdgcn_mfma_f32_16x16x32_bf16(a, b, c, 0, 0, 0);
}

// async global->LDS, 16B per lane, dest = wave-uniform base + lane*16
__device__ __forceinline__ void gload16(const u16* g, u16* l) {
    __builtin_amdgcn_global_load_lds(
        (const __attribute__((address_space(1))) void*)g,
        (__attribute__((address_space(3))) void*)l, 16, 0, 0);
}

// =====================================================================
// prep: cast/transpose weights to bf16 W^T  +  build padded bias+mask table
// total items: 1,048,576 weights + 2,097,152 bm = 3,145,728 -> grid 12288
// =====================================================================
__global__ __launch_bounds__(256)
void prep_kernel(const float* __restrict__ wqkv, const float* __restrict__ wproj,
                 const float* __restrict__ wfc1, const float* __restrict__ wfc2,
                 const float* __restrict__ relb, const float* __restrict__ amask,
                 u16* __restrict__ wqkvT, u16* __restrict__ wprojT,
                 u16* __restrict__ wfc1T, u16* __restrict__ wfc2T,
                 float* __restrict__ bm)
{
    int idx = blockIdx.x * 256 + threadIdx.x;
    if (idx < 196608) { int n = idx >> 8, k = idx & 255; wqkvT[idx] = f2b(wqkv[k*768 + n]); return; }
    idx -= 196608;
    if (idx < 65536)  { int n = idx >> 8, k = idx & 255; wprojT[idx] = f2b(wproj[k*256 + n]); return; }
    idx -= 65536;
    if (idx < 262144) { int n = idx >> 8, k = idx & 255; wfc1T[idx] = f2b(wfc1[k*1024 + n]); return; }
    idx -= 262144;
    if (idx < 262144) { int n = idx >> 10, k = idx & 1023; wfc2T[idx] = f2b(wfc2[k*256 + n]); return; }
    idx -= 262144;
    // bm[widx][h][n][m], 64x8x64x64, pad = -1e30
    int m = idx & 63, t = idx >> 6;
    int n = t & 63; t >>= 6;
    int h = t & 7;  t >>= 3;      // t = widx
    float v = -1e30f;
    if (n < 49 && m < 49) {
        int iq = n / 7, jq = n - iq * 7, ik = m / 7, jk = m - ik * 7;
        int rel = (iq - ik + 6) * 13 + (jq - jk + 6);
        v = relb[rel * 8 + h] + amask[(t * 49 + n) * 49 + m];
    }
    bm[idx] = v;
}

// =====================================================================
// LayerNorm (1 wave per 256-ch row).  mode 0: LN1 + cyclic shift + window
// partition (src gather).  mode 1: plain LN2.  Output bf16.
// =====================================================================
__global__ __launch_bounds__(256)
void ln_kernel(const float* __restrict__ x, const float* __restrict__ g,
               const float* __restrict__ be, u16* __restrict__ out, const int mode)
{
    const int wid  = ((blockIdx.x << 8) + threadIdx.x) >> 6;  // row 0..50175
    const int lane = threadIdx.x & 63;
    size_t srcoff;
    if (mode == 0) {
        int bw = wid / 49, nt = wid - bw * 49;
        int b = bw >> 6, widx = bw & 63;
        int wh = widx >> 3, ww = widx & 7;
        int ti = nt / 7, tj = nt - ti * 7;
        int hh = wh * 7 + ti + 3; if (hh >= 56) hh -= 56;   // roll(-3): src=(dst+3)%56
        int wp = ww * 7 + tj + 3; if (wp >= 56) wp -= 56;
        srcoff = ((size_t)b * 3136 + hh * 56 + wp) << 8;
    } else {
        srcoff = (size_t)wid << 8;
    }
    float4 v = *(const float4*)(x + srcoff + (lane << 2));
    float s  = v.x + v.y + v.z + v.w;
    float s2 = fmaf(v.x, v.x, fmaf(v.y, v.y, fmaf(v.z, v.z, v.w * v.w)));
    #pragma unroll
    for (int k = 1; k < 64; k <<= 1) { s += __shfl_xor(s, k); s2 += __shfl_xor(s2, k); }
    const float mu   = s * 0.00390625f;
    const float rstd = rsqrtf(s2 * 0.00390625f - mu * mu + 1e-5f);
    float4 gv = *(const float4*)(g  + (lane << 2));
    float4 bv = *(const float4*)(be + (lane << 2));
    ushort4 o;
    o.x = f2b((v.x - mu) * rstd * gv.x + bv.x);
    o.y = f2b((v.y - mu) * rstd * gv.y + bv.y);
    o.z = f2b((v.z - mu) * rstd * gv.z + bv.z);
    o.w = f2b((v.w - mu) * rstd * gv.w + bv.w);
    *(ushort4*)(out + ((size_t)wid << 8) + (lane << 2)) = o;
}

// =====================================================================
// 128x128 bf16 MFMA GEMM, BK=32, 4 waves (2x2 of 64x64).
// Staging via global_load_lds width=16.  LDS layout [chunk][row] of 16B
// cells: DMA dest = wave-uniform base + lane*16 (lane = tile row), and
// fragment ds_read_b128 is conflict-free (2-way = free per m136).
// MODE 0: +bias -> bf16          (qkv)
// MODE 1: +bias, scatter window_reverse+roll, += resid(x_in) -> f32 (proj->x2)
// MODE 2: gelu(+bias) -> bf16    (fc1)
// MODE 3: +bias += resid(x2) -> f32 (fc2 -> d_out)
// =====================================================================
template<int MODE>
__global__ __launch_bounds__(256)
void gemm128(const u16* __restrict__ A, const u16* __restrict__ Bt,
             const float* __restrict__ bias, void* __restrict__ Cout,
             const int N, const int K, const float* __restrict__ resid)
{
    __shared__ __align__(16) u16 As[4 * 128 * 8];   // [chunk c][row][8 k-elems]
    __shared__ __align__(16) u16 Bs[4 * 128 * 8];

    const int tid  = threadIdx.x;
    const int wave = tid >> 6, lane = tid & 63;
    const int q = lane >> 4, l15 = lane & 15;
    const int wm = wave >> 1, wn = wave & 1;
    const int m0 = blockIdx.y << 7, n0 = blockIdx.x << 7;

    f32x4 acc[4][4] = {};

    // wave w stages k-chunk c=w (8 bf16 = 16B per row), both 64-row halves
    const u16* Ag = A  + (size_t)(m0 + lane) * K + wave * 8;
    const u16* Bg = Bt + (size_t)(n0 + lane) * K + wave * 8;
    const size_t half = (size_t)64 * K;
    u16* lA0 = &As[(wave * 128 +  0) * 8];
    u16* lA1 = &As[(wave * 128 + 64) * 8];
    u16* lB0 = &Bs[(wave * 128 +  0) * 8];
    u16* lB1 = &Bs[(wave * 128 + 64) * 8];

    const int KT = K >> 5;
    for (int kt = 0; kt < KT; ++kt) {
        const int ko = kt * 32;
        gload16(Ag + ko, lA0);
        gload16(Ag + ko + half, lA1);
        gload16(Bg + ko, lB0);
        gload16(Bg + ko + half, lB1);
        // explicit DMA drain (defensive: ensure barrier semantics cover the
        // LDS-DMA queue on this ROCm; free if the compiler emits it anyway)
        asm volatile("s_waitcnt vmcnt(0)" ::: "memory");
        __syncthreads();                        // tile visible to all waves
        bf16x8 af[4], bfv[4];
        #pragma unroll
        for (int i = 0; i < 4; ++i)
            af[i] = *(const bf16x8*)&As[(q * 128 + wm * 64 + i * 16 + l15) * 8];
        #pragma unroll
        for (int j = 0; j < 4; ++j)
            bfv[j] = *(const bf16x8*)&Bs[(q * 128 + wn * 64 + j * 16 + l15) * 8];
        #pragma unroll
        for (int i = 0; i < 4; ++i)
            #pragma unroll
            for (int j = 0; j < 4; ++j)
                acc[i][j] = mfma16(af[i], bfv[j], acc[i][j]);
        __syncthreads();                        // frags consumed: safe to overwrite
    }

    // epilogue: row = m0+wm*64+i*16+q*4+r, col = n0+wn*64+j*16+l15
    #pragma unroll
    for (int i = 0; i < 4; ++i) {
        #pragma unroll
        for (int r = 0; r < 4; ++r) {
            const int m = m0 + wm * 64 + i * 16 + q * 4 + r;
            size_t dstrow = 0;
            if (MODE == 1) {
                int bw = m / 49, nt = m - bw * 49;
                int b = bw >> 6, widx = bw & 63;
                int wh = widx >> 3, ww2 = widx & 7;
                int ti = nt / 7, tj = nt - ti * 7;
                int hh = wh * 7 + ti + 3;  if (hh >= 56) hh -= 56;  // roll(+3)
                int wp = ww2 * 7 + tj + 3; if (wp >= 56) wp -= 56;
                dstrow = ((size_t)b * 3136 + hh * 56 + wp) << 8;
            }
            #pragma unroll
            for (int j = 0; j < 4; ++j) {
                const int col = n0 + wn * 64 + j * 16 + l15;
                float v = acc[i][j][r] + bias[col];
                if (MODE == 0) {
                    ((u16*)Cout)[(size_t)m * N + col] = f2b(v);
                } else if (MODE == 2) {
                    v = 0.5f * v * (1.0f + erff(v * 0.70710678118654752f));
                    ((u16*)Cout)[(size_t)m * N + col] = f2b(v);
                } else if (MODE == 3) {
                    const size_t o = (size_t)m * N + col;
                    ((float*)Cout)[o] = resid[o] + v;
                } else { // MODE 1
                    const size_t o = dstrow + col;
                    ((float*)Cout)[o] = resid[o] + v;
                }
            }
        }
    }
}

// =====================================================================
// Attention: 1 wave per (window, head). head_dim=32 == one MFMA K-step.
// =====================================================================
__global__ __launch_bounds__(64)
void attn_kernel(const u16* __restrict__ qkv, const float* __restrict__ bm,
                 u16* __restrict__ out)
{
    constexpr int LDP = 72;   // padded stride (16B-aligned: 72*2=144)
    __shared__ __align__(16) u16 Pl[64 * LDP];
    __shared__ __align__(16) u16 Vt[32 * LDP];

    const int bw   = blockIdx.x >> 3;
    const int h    = blockIdx.x & 7;
    const int widx = bw & 63;
    const int lane = threadIdx.x;
    const int q = lane >> 4, l15 = lane & 15;

    const u16* base = qkv + (size_t)bw * 49 * 768 + h * 32;

    // stage V^T (keys >= 49 zeroed)
    {
        const int key = lane;
        const u16* vp = base + 512 + (size_t)(key < 49 ? key : 0) * 768;
        __align__(16) u16 tmp[32];
        #pragma unroll
        for (int c = 0; c < 4; ++c)
            *(u32x4*)&tmp[c * 8] = *(const u32x4*)(vp + c * 8);
        #pragma unroll
        for (int d = 0; d < 32; ++d)
            Vt[d * LDP + key] = (key < 49) ? tmp[d] : (u16)0;
    }

    // Q K^T
    bf16x8 aq[4], bk[4];
    #pragma unroll
    for (int i = 0; i < 4; ++i) {
        int row = i * 16 + l15; row = (row < 49) ? row : 0;
        aq[i] = *(const bf16x8*)(base + (size_t)row * 768 + q * 8);
    }
    #pragma unroll
    for (int j = 0; j < 4; ++j) {
        int key = j * 16 + l15; key = (key < 49) ? key : 0;
        bk[j] = *(const bf16x8*)(base + (size_t)key * 768 + 256 + q * 8);
    }
    f32x4 s[4][4];
    #pragma unroll
    for (int i = 0; i < 4; ++i)
        #pragma unroll
        for (int j = 0; j < 4; ++j) {
            f32x4 z = {0.f, 0.f, 0.f, 0.f};
            s[i][j] = mfma16(aq[i], bk[j], z);
        }

    // scale + (rel bias + mask) from padded table
    const float* bmb = bm + ((size_t)(widx * 8 + h) << 12);
    #pragma unroll
    for (int i = 0; i < 4; ++i) {
        #pragma unroll
        for (int r = 0; r < 4; ++r) {
            const int n = i * 16 + q * 4 + r;
            const float* rowp = bmb + (n << 6) + l15;
            #pragma unroll
            for (int j = 0; j < 4; ++j)
                s[i][j][r] = fmaf(s[i][j][r], SCALE_F, rowp[j * 16]);
        }
    }

    // softmax per row; write P (bf16) to LDS in row-major A-layout
    #pragma unroll
    for (int i = 0; i < 4; ++i) {
        #pragma unroll
        for (int r = 0; r < 4; ++r) {
            float mx = fmaxf(fmaxf(s[i][0][r], s[i][1][r]), fmaxf(s[i][2][r], s[i][3][r]));
            #pragma unroll
            for (int k = 1; k < 16; k <<= 1) mx = fmaxf(mx, __shfl_xor(mx, k));
            float p[4], sum = 0.f;
            #pragma unroll
            for (int j = 0; j < 4; ++j) { p[j] = __expf(s[i][j][r] - mx); sum += p[j]; }
            #pragma unroll
            for (int k = 1; k < 16; k <<= 1) sum += __shfl_xor(sum, k);
            const float inv = 1.0f / sum;
            const int n = i * 16 + q * 4 + r;
            #pragma unroll
            for (int j = 0; j < 4; ++j)
                Pl[n * LDP + j * 16 + l15] = f2b(p[j] * inv);
        }
    }
    __syncthreads();

    // O = P V
    f32x4 o[4][2] = {};
    #pragma unroll
    for (int ks = 0; ks < 2; ++ks) {
        bf16x8 ap[4], bv[2];
        #pragma unroll
        for (int i = 0; i < 4; ++i)
            ap[i] = *(const bf16x8*)&Pl[(i * 16 + l15) * LDP + ks * 32 + q * 8];
        #pragma unroll
        for (int jd = 0; jd < 2; ++jd)
            bv[jd] = *(const bf16x8*)&Vt[(jd * 16 + l15) * LDP + ks * 32 + q * 8];
        #pragma unroll
        for (int i = 0; i < 4; ++i)
            #pragma unroll
            for (int jd = 0; jd < 2; ++jd)
                o[i][jd] = mfma16(ap[i], bv[jd], o[i][jd]);
    }

    #pragma unroll
    for (int i = 0; i < 4; ++i) {
        #pragma unroll
        for (int r = 0; r < 4; ++r) {
            const int n = i * 16 + q * 4 + r;
            if (n < 49) {
                u16* op = out + ((size_t)(bw * 49 + n) << 8) + h * 32;
                #pragma unroll
                for (int jd = 0; jd < 2; ++jd)
                    op[jd * 16 + l15] = f2b(o[i][jd][r]);
            }
        }
    }
}

// =====================================================================
extern "C" void kernel_launch(void* const* d_in, const int* in_sizes, int n_in,
                              void* d_out, int out_size, void* d_ws, size_t ws_size,
                              hipStream_t stream) {
    const float* x      = (const float*)d_in[0];
    const float* w_qkv  = (const float*)d_in[1];
    const float* b_qkv  = (const float*)d_in[2];
    const float* rel_b  = (const float*)d_in[3];
    const float* w_proj = (const float*)d_in[4];
    const float* b_proj = (const float*)d_in[5];
    const float* g1     = (const float*)d_in[6];
    const float* be1    = (const float*)d_in[7];
    const float* g2     = (const float*)d_in[8];
    const float* be2    = (const float*)d_in[9];
    const float* w_fc1  = (const float*)d_in[10];
    const float* b_fc1  = (const float*)d_in[11];
    const float* w_fc2  = (const float*)d_in[12];
    const float* b_fc2  = (const float*)d_in[13];
    const float* amask  = (const float*)d_in[14];

    char* ws = (char*)d_ws;
    u16*   xw     = (u16*)(ws);                 // 50176*256 bf16 = 25,690,112
    u16*   qkvb   = (u16*)(ws + 25690112);      // 50176*768 bf16 = 77,070,336
    u16*   attno  = (u16*)(ws + 102760448);     // 50176*256 bf16 = 25,690,112
    float* x2     = (float*)(ws + 128450560);   // 50176*256 f32  = 51,380,224
    u16*   wqkvT  = (u16*)(ws + 179830784);     // 393,216
    u16*   wprojT = (u16*)(ws + 180224000);     // 131,072
    u16*   wfc1T  = (u16*)(ws + 180355072);     // 524,288
    u16*   wfc2T  = (u16*)(ws + 180879360);     // 524,288
    float* bm     = (float*)(ws + 181403648);   // 64*8*64*64 f32 = 8,388,608
    u16*   h1     = qkvb;                       // fc1 out reuses qkv+attno region

    prep_kernel<<<12288, 256, 0, stream>>>(w_qkv, w_proj, w_fc1, w_fc2, rel_b, amask,
                                           wqkvT, wprojT, wfc1T, wfc2T, bm);
    ln_kernel<<<12544, 256, 0, stream>>>(x, g1, be1, xw, 0);
    gemm128<0><<<dim3(6, 392), 256, 0, stream>>>(xw, wqkvT, b_qkv, qkvb, 768, 256, nullptr);
    attn_kernel<<<8192, 64, 0, stream>>>(qkvb, bm, attno);
    gemm128<1><<<dim3(2, 392), 256, 0, stream>>>(attno, wprojT, b_proj, x2, 256, 256, x);
    ln_kernel<<<12544, 256, 0, stream>>>(x2, g2, be2, xw, 1);
    gemm128<2><<<dim3(8, 392), 256, 0, stream>>>(xw, wfc1T, b_fc1, h1, 1024, 256, nullptr);
    gemm128<3><<<dim3(2, 392), 256, 0, stream>>>(h1, wfc2T, b_fc2, (float*)d_out, 256, 1024, x2);
}

// Round 5
// 375.360 us; speedup vs baseline: 1.1975x; 1.1975x over previous
//
#include <hip/hip_runtime.h>
#include <hip/hip_bf16.h>

typedef unsigned short u16;
typedef __bf16 bf16x8 __attribute__((ext_vector_type(8)));
typedef float f32x4 __attribute__((ext_vector_type(4)));
typedef unsigned int u32x4 __attribute__((ext_vector_type(4)));

#define SCALE_F 0.17677669529663687f

__device__ __forceinline__ u16 f2b(float f) {
    unsigned u = __builtin_bit_cast(unsigned, f);
    u = (u + 0x7fffu + ((u >> 16) & 1u)) >> 16;   // RNE, no NaN in our data
    return (u16)u;
}

__device__ __forceinline__ f32x4 mfma16(bf16x8 a, bf16x8 b, f32x4 c) {
    return __builtin_amdgcn_mfma_f32_16x16x32_bf16(a, b, c, 0, 0, 0);
}

// =====================================================================
// prep: cast/transpose weights to bf16 W^T  +  build padded bias+mask table
// total items: 1,048,576 weights + 2,097,152 bm = 3,145,728 -> grid 12288
// =====================================================================
__global__ __launch_bounds__(256)
void prep_kernel(const float* __restrict__ wqkv, const float* __restrict__ wproj,
                 const float* __restrict__ wfc1, const float* __restrict__ wfc2,
                 const float* __restrict__ relb, const float* __restrict__ amask,
                 u16* __restrict__ wqkvT, u16* __restrict__ wprojT,
                 u16* __restrict__ wfc1T, u16* __restrict__ wfc2T,
                 float* __restrict__ bm)
{
    int idx = blockIdx.x * 256 + threadIdx.x;
    if (idx < 196608) { int n = idx >> 8, k = idx & 255; wqkvT[idx] = f2b(wqkv[k*768 + n]); return; }
    idx -= 196608;
    if (idx < 65536)  { int n = idx >> 8, k = idx & 255; wprojT[idx] = f2b(wproj[k*256 + n]); return; }
    idx -= 65536;
    if (idx < 262144) { int n = idx >> 8, k = idx & 255; wfc1T[idx] = f2b(wfc1[k*1024 + n]); return; }
    idx -= 262144;
    if (idx < 262144) { int n = idx >> 10, k = idx & 1023; wfc2T[idx] = f2b(wfc2[k*256 + n]); return; }
    idx -= 262144;
    // bm[widx][h][n][m], 64x8x64x64, pad = -1e30
    int m = idx & 63, t = idx >> 6;
    int n = t & 63; t >>= 6;
    int h = t & 7;  t >>= 3;      // t = widx
    float v = -1e30f;
    if (n < 49 && m < 49) {
        int iq = n / 7, jq = n - iq * 7, ik = m / 7, jk = m - ik * 7;
        int rel = (iq - ik + 6) * 13 + (jq - jk + 6);
        v = relb[rel * 8 + h] + amask[(t * 49 + n) * 49 + m];
    }
    bm[idx] = v;
}

// =====================================================================
// LayerNorm (1 wave per 256-ch row).  mode 0: LN1 + cyclic shift + window
// partition (src gather).  mode 1: plain LN2.  Output bf16.
// =====================================================================
__global__ __launch_bounds__(256)
void ln_kernel(const float* __restrict__ x, const float* __restrict__ g,
               const float* __restrict__ be, u16* __restrict__ out, const int mode)
{
    const int wid  = ((blockIdx.x << 8) + threadIdx.x) >> 6;  // row 0..50175
    const int lane = threadIdx.x & 63;
    size_t srcoff;
    if (mode == 0) {
        int bw = wid / 49, nt = wid - bw * 49;
        int b = bw >> 6, widx = bw & 63;
        int wh = widx >> 3, ww = widx & 7;
        int ti = nt / 7, tj = nt - ti * 7;
        int hh = wh * 7 + ti + 3; if (hh >= 56) hh -= 56;   // roll(-3): src=(dst+3)%56
        int wp = ww * 7 + tj + 3; if (wp >= 56) wp -= 56;
        srcoff = ((size_t)b * 3136 + hh * 56 + wp) << 8;
    } else {
        srcoff = (size_t)wid << 8;
    }
    float4 v = *(const float4*)(x + srcoff + (lane << 2));
    float s  = v.x + v.y + v.z + v.w;
    float s2 = fmaf(v.x, v.x, fmaf(v.y, v.y, fmaf(v.z, v.z, v.w * v.w)));
    #pragma unroll
    for (int k = 1; k < 64; k <<= 1) { s += __shfl_xor(s, k); s2 += __shfl_xor(s2, k); }
    const float mu   = s * 0.00390625f;
    const float rstd = rsqrtf(s2 * 0.00390625f - mu * mu + 1e-5f);
    float4 gv = *(const float4*)(g  + (lane << 2));
    float4 bv = *(const float4*)(be + (lane << 2));
    ushort4 o;
    o.x = f2b((v.x - mu) * rstd * gv.x + bv.x);
    o.y = f2b((v.y - mu) * rstd * gv.y + bv.y);
    o.z = f2b((v.z - mu) * rstd * gv.z + bv.z);
    o.w = f2b((v.w - mu) * rstd * gv.w + bv.w);
    *(ushort4*)(out + ((size_t)wid << 8) + (lane << 2)) = o;
}

// =====================================================================
// 128x128 bf16 MFMA GEMM, BK=32, 4 waves (2x2 of 64x64), register
// staging with 1-tile register prefetch (measured faster than the
// no-prefetch global_load_lds loop: 79.9 vs 99.5 us on fc1 — the DMA
// path serializes the full load latency behind every barrier).
// LDA=40 padding: 2-way LDS aliasing only (free per m136).
// MODE 0: +bias -> bf16          (qkv)
// MODE 1: +bias, scatter window_reverse+roll, += resid(x_in) -> f32 (proj->x2)
// MODE 2: gelu(+bias) -> bf16    (fc1)   [tanh-form gelu, ~7 VALU ops]
// MODE 3: +bias += resid(x2) -> f32 (fc2 -> d_out)
// =====================================================================
template<int MODE>
__global__ __launch_bounds__(256)
void gemm128(const u16* __restrict__ A, const u16* __restrict__ Bt,
             const float* __restrict__ bias, void* __restrict__ Cout,
             const int N, const int K, const float* __restrict__ resid)
{
    constexpr int LDA = 40;   // padded LDS stride
    __shared__ __align__(16) u16 As[128 * LDA];
    __shared__ __align__(16) u16 Bs[128 * LDA];

    const int tid  = threadIdx.x;
    const int wave = tid >> 6, lane = tid & 63;
    const int q = lane >> 4, l15 = lane & 15;
    const int wm = wave >> 1, wn = wave & 1;
    const int m0 = blockIdx.y << 7, n0 = blockIdx.x << 7;

    f32x4 acc[4][4] = {};

    const int ar = tid >> 2;
    const int ac = (tid & 3) << 3;
    const u16* Ag = A  + (size_t)(m0 + ar) * K + ac;
    const u16* Bg = Bt + (size_t)(n0 + ar) * K + ac;
    const size_t rstep = (size_t)64 * K;

    u32x4 ra0 = *(const u32x4*)Ag;
    u32x4 ra1 = *(const u32x4*)(Ag + rstep);
    u32x4 rb0 = *(const u32x4*)Bg;
    u32x4 rb1 = *(const u32x4*)(Bg + rstep);

    const int KT = K >> 5;
    for (int kt = 0; kt < KT; ++kt) {
        __syncthreads();
        *(u32x4*)&As[ar * LDA + ac]        = ra0;
        *(u32x4*)&As[(ar + 64) * LDA + ac] = ra1;
        *(u32x4*)&Bs[ar * LDA + ac]        = rb0;
        *(u32x4*)&Bs[(ar + 64) * LDA + ac] = rb1;
        if (kt + 1 < KT) {
            const u16* Ag2 = Ag + (kt + 1) * 32;
            const u16* Bg2 = Bg + (kt + 1) * 32;
            ra0 = *(const u32x4*)Ag2;
            ra1 = *(const u32x4*)(Ag2 + rstep);
            rb0 = *(const u32x4*)Bg2;
            rb1 = *(const u32x4*)(Bg2 + rstep);
        }
        __syncthreads();
        bf16x8 af[4], bfv[4];
        #pragma unroll
        for (int i = 0; i < 4; ++i)
            af[i] = *(const bf16x8*)&As[(wm * 64 + i * 16 + l15) * LDA + q * 8];
        #pragma unroll
        for (int j = 0; j < 4; ++j)
            bfv[j] = *(const bf16x8*)&Bs[(wn * 64 + j * 16 + l15) * LDA + q * 8];
        #pragma unroll
        for (int i = 0; i < 4; ++i)
            #pragma unroll
            for (int j = 0; j < 4; ++j)
                acc[i][j] = mfma16(af[i], bfv[j], acc[i][j]);
    }

    // epilogue: row = m0+wm*64+i*16+q*4+r, col = n0+wn*64+j*16+l15
    #pragma unroll
    for (int i = 0; i < 4; ++i) {
        #pragma unroll
        for (int r = 0; r < 4; ++r) {
            const int m = m0 + wm * 64 + i * 16 + q * 4 + r;
            size_t dstrow = 0;
            if (MODE == 1) {
                int bw = m / 49, nt = m - bw * 49;
                int b = bw >> 6, widx = bw & 63;
                int wh = widx >> 3, ww2 = widx & 7;
                int ti = nt / 7, tj = nt - ti * 7;
                int hh = wh * 7 + ti + 3;  if (hh >= 56) hh -= 56;  // roll(+3)
                int wp = ww2 * 7 + tj + 3; if (wp >= 56) wp -= 56;
                dstrow = ((size_t)b * 3136 + hh * 56 + wp) << 8;
            }
            #pragma unroll
            for (int j = 0; j < 4; ++j) {
                const int col = n0 + wn * 64 + j * 16 + l15;
                float v = acc[i][j][r] + bias[col];
                if (MODE == 0) {
                    ((u16*)Cout)[(size_t)m * N + col] = f2b(v);
                } else if (MODE == 2) {
                    // tanh-form gelu: x*(1 - 1/(1+e^{2y})), y = a(x+bx^3)
                    float y = 0.7978845608028654f * (v + 0.044715f * v * v * v);
                    float t = __expf(2.0f * y);
                    float rr = __builtin_amdgcn_rcpf(t + 1.0f);
                    v = v - v * rr;
                    ((u16*)Cout)[(size_t)m * N + col] = f2b(v);
                } else if (MODE == 3) {
                    const size_t o = (size_t)m * N + col;
                    ((float*)Cout)[o] = resid[o] + v;
                } else { // MODE 1
                    const size_t o = dstrow + col;
                    ((float*)Cout)[o] = resid[o] + v;
                }
            }
        }
    }
}

// =====================================================================
// Attention: 1 wave per (window, head). head_dim=32 == one MFMA K-step.
// =====================================================================
__global__ __launch_bounds__(64)
void attn_kernel(const u16* __restrict__ qkv, const float* __restrict__ bm,
                 u16* __restrict__ out)
{
    constexpr int LDP = 72;   // padded stride (16B-aligned: 72*2=144)
    __shared__ __align__(16) u16 Pl[64 * LDP];
    __shared__ __align__(16) u16 Vt[32 * LDP];

    const int bw   = blockIdx.x >> 3;
    const int h    = blockIdx.x & 7;
    const int widx = bw & 63;
    const int lane = threadIdx.x;
    const int q = lane >> 4, l15 = lane & 15;

    const u16* base = qkv + (size_t)bw * 49 * 768 + h * 32;

    // stage V^T (keys >= 49 zeroed)
    {
        const int key = lane;
        const u16* vp = base + 512 + (size_t)(key < 49 ? key : 0) * 768;
        __align__(16) u16 tmp[32];
        #pragma unroll
        for (int c = 0; c < 4; ++c)
            *(u32x4*)&tmp[c * 8] = *(const u32x4*)(vp + c * 8);
        #pragma unroll
        for (int d = 0; d < 32; ++d)
            Vt[d * LDP + key] = (key < 49) ? tmp[d] : (u16)0;
    }

    // Q K^T
    bf16x8 aq[4], bk[4];
    #pragma unroll
    for (int i = 0; i < 4; ++i) {
        int row = i * 16 + l15; row = (row < 49) ? row : 0;
        aq[i] = *(const bf16x8*)(base + (size_t)row * 768 + q * 8);
    }
    #pragma unroll
    for (int j = 0; j < 4; ++j) {
        int key = j * 16 + l15; key = (key < 49) ? key : 0;
        bk[j] = *(const bf16x8*)(base + (size_t)key * 768 + 256 + q * 8);
    }
    f32x4 s[4][4];
    #pragma unroll
    for (int i = 0; i < 4; ++i)
        #pragma unroll
        for (int j = 0; j < 4; ++j) {
            f32x4 z = {0.f, 0.f, 0.f, 0.f};
            s[i][j] = mfma16(aq[i], bk[j], z);
        }

    // scale + (rel bias + mask) from padded table
    const float* bmb = bm + ((size_t)(widx * 8 + h) << 12);
    #pragma unroll
    for (int i = 0; i < 4; ++i) {
        #pragma unroll
        for (int r = 0; r < 4; ++r) {
            const int n = i * 16 + q * 4 + r;
            const float* rowp = bmb + (n << 6) + l15;
            #pragma unroll
            for (int j = 0; j < 4; ++j)
                s[i][j][r] = fmaf(s[i][j][r], SCALE_F, rowp[j * 16]);
        }
    }

    // softmax per row; write P (bf16) to LDS in row-major A-layout
    #pragma unroll
    for (int i = 0; i < 4; ++i) {
        #pragma unroll
        for (int r = 0; r < 4; ++r) {
            float mx = fmaxf(fmaxf(s[i][0][r], s[i][1][r]), fmaxf(s[i][2][r], s[i][3][r]));
            #pragma unroll
            for (int k = 1; k < 16; k <<= 1) mx = fmaxf(mx, __shfl_xor(mx, k));
            float p[4], sum = 0.f;
            #pragma unroll
            for (int j = 0; j < 4; ++j) { p[j] = __expf(s[i][j][r] - mx); sum += p[j]; }
            #pragma unroll
            for (int k = 1; k < 16; k <<= 1) sum += __shfl_xor(sum, k);
            const float inv = 1.0f / sum;
            const int n = i * 16 + q * 4 + r;
            #pragma unroll
            for (int j = 0; j < 4; ++j)
                Pl[n * LDP + j * 16 + l15] = f2b(p[j] * inv);
        }
    }
    __syncthreads();

    // O = P V
    f32x4 o[4][2] = {};
    #pragma unroll
    for (int ks = 0; ks < 2; ++ks) {
        bf16x8 ap[4], bv[2];
        #pragma unroll
        for (int i = 0; i < 4; ++i)
            ap[i] = *(const bf16x8*)&Pl[(i * 16 + l15) * LDP + ks * 32 + q * 8];
        #pragma unroll
        for (int jd = 0; jd < 2; ++jd)
            bv[jd] = *(const bf16x8*)&Vt[(jd * 16 + l15) * LDP + ks * 32 + q * 8];
        #pragma unroll
        for (int i = 0; i < 4; ++i)
            #pragma unroll
            for (int jd = 0; jd < 2; ++jd)
                o[i][jd] = mfma16(ap[i], bv[jd], o[i][jd]);
    }

    #pragma unroll
    for (int i = 0; i < 4; ++i) {
        #pragma unroll
        for (int r = 0; r < 4; ++r) {
            const int n = i * 16 + q * 4 + r;
            if (n < 49) {
                u16* op = out + ((size_t)(bw * 49 + n) << 8) + h * 32;
                #pragma unroll
                for (int jd = 0; jd < 2; ++jd)
                    op[jd * 16 + l15] = f2b(o[i][jd][r]);
            }
        }
    }
}

// =====================================================================
extern "C" void kernel_launch(void* const* d_in, const int* in_sizes, int n_in,
                              void* d_out, int out_size, void* d_ws, size_t ws_size,
                              hipStream_t stream) {
    const float* x      = (const float*)d_in[0];
    const float* w_qkv  = (const float*)d_in[1];
    const float* b_qkv  = (const float*)d_in[2];
    const float* rel_b  = (const float*)d_in[3];
    const float* w_proj = (const float*)d_in[4];
    const float* b_proj = (const float*)d_in[5];
    const float* g1     = (const float*)d_in[6];
    const float* be1    = (const float*)d_in[7];
    const float* g2     = (const float*)d_in[8];
    const float* be2    = (const float*)d_in[9];
    const float* w_fc1  = (const float*)d_in[10];
    const float* b_fc1  = (const float*)d_in[11];
    const float* w_fc2  = (const float*)d_in[12];
    const float* b_fc2  = (const float*)d_in[13];
    const float* amask  = (const float*)d_in[14];

    char* ws = (char*)d_ws;
    u16*   xw     = (u16*)(ws);                 // 50176*256 bf16 = 25,690,112
    u16*   qkvb   = (u16*)(ws + 25690112);      // 50176*768 bf16 = 77,070,336
    u16*   attno  = (u16*)(ws + 102760448);     // 50176*256 bf16 = 25,690,112
    float* x2     = (float*)(ws + 128450560);   // 50176*256 f32  = 51,380,224
    u16*   wqkvT  = (u16*)(ws + 179830784);     // 393,216
    u16*   wprojT = (u16*)(ws + 180224000);     // 131,072
    u16*   wfc1T  = (u16*)(ws + 180355072);     // 524,288
    u16*   wfc2T  = (u16*)(ws + 180879360);     // 524,288
    float* bm     = (float*)(ws + 181403648);   // 64*8*64*64 f32 = 8,388,608
    u16*   h1     = qkvb;                       // fc1 out reuses qkv+attno region

    prep_kernel<<<12288, 256, 0, stream>>>(w_qkv, w_proj, w_fc1, w_fc2, rel_b, amask,
                                           wqkvT, wprojT, wfc1T, wfc2T, bm);
    ln_kernel<<<12544, 256, 0, stream>>>(x, g1, be1, xw, 0);
    gemm128<0><<<dim3(6, 392), 256, 0, stream>>>(xw, wqkvT, b_qkv, qkvb, 768, 256, nullptr);
    attn_kernel<<<8192, 64, 0, stream>>>(qkvb, bm, attno);
    gemm128<1><<<dim3(2, 392), 256, 0, stream>>>(attno, wprojT, b_proj, x2, 256, 256, x);
    ln_kernel<<<12544, 256, 0, stream>>>(x2, g2, be2, xw, 1);
    gemm128<2><<<dim3(8, 392), 256, 0, stream>>>(xw, wfc1T, b_fc1, h1, 1024, 256, nullptr);
    gemm128<3><<<dim3(2, 392), 256, 0, stream>>>(h1, wfc2T, b_fc2, (float*)d_out, 256, 1024, x2);
}

// Round 6
// 348.449 us; speedup vs baseline: 1.2900x; 1.0772x over previous
//
#include <hip/hip_runtime.h>
#include <hip/hip_bf16.h>

typedef unsigned short u16;
typedef __bf16 bf16x8 __attribute__((ext_vector_type(8)));
typedef float f32x4 __attribute__((ext_vector_type(4)));
typedef unsigned int u32x4 __attribute__((ext_vector_type(4)));

#define SCALE_F 0.17677669529663687f

__device__ __forceinline__ u16 f2b(float f) {
    unsigned u = __builtin_bit_cast(unsigned, f);
    u = (u + 0x7fffu + ((u >> 16) & 1u)) >> 16;   // RNE, no NaN in our data
    return (u16)u;
}
__device__ __forceinline__ float b2f(u16 b) {
    unsigned u = ((unsigned)b) << 16;
    return __builtin_bit_cast(float, u);
}

__device__ __forceinline__ f32x4 mfma16(bf16x8 a, bf16x8 b, f32x4 c) {
    return __builtin_amdgcn_mfma_f32_16x16x32_bf16(a, b, c, 0, 0, 0);
}

// =====================================================================
// prep: cast/transpose weights to bf16 W^T  +  build padded bias+mask table
// total items: 1,048,576 weights + 2,097,152 bm = 3,145,728 -> grid 12288
// =====================================================================
__global__ __launch_bounds__(256)
void prep_kernel(const float* __restrict__ wqkv, const float* __restrict__ wproj,
                 const float* __restrict__ wfc1, const float* __restrict__ wfc2,
                 const float* __restrict__ relb, const float* __restrict__ amask,
                 u16* __restrict__ wqkvT, u16* __restrict__ wprojT,
                 u16* __restrict__ wfc1T, u16* __restrict__ wfc2T,
                 float* __restrict__ bm)
{
    int idx = blockIdx.x * 256 + threadIdx.x;
    if (idx < 196608) { int n = idx >> 8, k = idx & 255; wqkvT[idx] = f2b(wqkv[k*768 + n]); return; }
    idx -= 196608;
    if (idx < 65536)  { int n = idx >> 8, k = idx & 255; wprojT[idx] = f2b(wproj[k*256 + n]); return; }
    idx -= 65536;
    if (idx < 262144) { int n = idx >> 8, k = idx & 255; wfc1T[idx] = f2b(wfc1[k*1024 + n]); return; }
    idx -= 262144;
    if (idx < 262144) { int n = idx >> 10, k = idx & 1023; wfc2T[idx] = f2b(wfc2[k*256 + n]); return; }
    idx -= 262144;
    // bm[widx][h][n][m], 64x8x64x64, pad = -1e30
    int m = idx & 63, t = idx >> 6;
    int n = t & 63; t >>= 6;
    int h = t & 7;  t >>= 3;      // t = widx
    float v = -1e30f;
    if (n < 49 && m < 49) {
        int iq = n / 7, jq = n - iq * 7, ik = m / 7, jk = m - ik * 7;
        int rel = (iq - ik + 6) * 13 + (jq - jk + 6);
        v = relb[rel * 8 + h] + amask[(t * 49 + n) * 49 + m];
    }
    bm[idx] = v;
}

// =====================================================================
// LayerNorm (1 wave per 256-ch row).  mode 0: LN1 + cyclic shift + window
// partition (f32 src gather).  mode 2: plain LN over bf16 input.
// Output bf16.
// =====================================================================
__global__ __launch_bounds__(256)
void ln_kernel(const float* __restrict__ x, const u16* __restrict__ xb,
               const float* __restrict__ g, const float* __restrict__ be,
               u16* __restrict__ out, const int mode)
{
    const int wid  = ((blockIdx.x << 8) + threadIdx.x) >> 6;  // row 0..50175
    const int lane = threadIdx.x & 63;
    float4 v;
    if (mode == 0) {
        int bw = wid / 49, nt = wid - bw * 49;
        int b = bw >> 6, widx = bw & 63;
        int wh = widx >> 3, ww = widx & 7;
        int ti = nt / 7, tj = nt - ti * 7;
        int hh = wh * 7 + ti + 3; if (hh >= 56) hh -= 56;   // roll(-3): src=(dst+3)%56
        int wp = ww * 7 + tj + 3; if (wp >= 56) wp -= 56;
        size_t srcoff = ((size_t)b * 3136 + hh * 56 + wp) << 8;
        v = *(const float4*)(x + srcoff + (lane << 2));
    } else {
        ushort4 raw = *(const ushort4*)(xb + ((size_t)wid << 8) + (lane << 2));
        v.x = b2f(raw.x); v.y = b2f(raw.y); v.z = b2f(raw.z); v.w = b2f(raw.w);
    }
    float s  = v.x + v.y + v.z + v.w;
    float s2 = fmaf(v.x, v.x, fmaf(v.y, v.y, fmaf(v.z, v.z, v.w * v.w)));
    #pragma unroll
    for (int k = 1; k < 64; k <<= 1) { s += __shfl_xor(s, k); s2 += __shfl_xor(s2, k); }
    const float mu   = s * 0.00390625f;
    const float rstd = rsqrtf(s2 * 0.00390625f - mu * mu + 1e-5f);
    float4 gv = *(const float4*)(g  + (lane << 2));
    float4 bv = *(const float4*)(be + (lane << 2));
    ushort4 o;
    o.x = f2b((v.x - mu) * rstd * gv.x + bv.x);
    o.y = f2b((v.y - mu) * rstd * gv.y + bv.y);
    o.z = f2b((v.z - mu) * rstd * gv.z + bv.z);
    o.w = f2b((v.w - mu) * rstd * gv.w + bv.w);
    *(ushort4*)(out + ((size_t)wid << 8) + (lane << 2)) = o;
}

// =====================================================================
// 128x128 bf16 MFMA GEMM, BK=32, 4 waves (2x2 of 64x64), register
// staging with 1-tile register prefetch.  LDA=40 pad (2-way = free).
// 1-D grid with XCD swizzle: xcd = bid&7, all NB col-blocks of a
// row-block run consecutively on the SAME XCD -> A-tile fetched from
// HBM once per row-block, re-served from that XCD's L2 (round-robin
// block->XCD dispatch heuristic; verify via FETCH_SIZE).
// MODE 0: +bias -> bf16          (qkv)
// MODE 1: +bias, scatter window_reverse+roll, += resid(x f32) -> bf16 (proj->x2b)
// MODE 2: gelu(+bias) -> bf16    (fc1)  [tanh-form gelu]
// MODE 3: +bias += resid(x2b bf16) -> f32 (fc2 -> d_out)
// =====================================================================
template<int MODE>
__global__ __launch_bounds__(256)
void gemm128(const u16* __restrict__ A, const u16* __restrict__ Bt,
             const float* __restrict__ bias, void* __restrict__ Cout,
             const int N, const int K, const void* __restrict__ resid,
             const int NB)
{
    constexpr int LDA = 40;   // padded LDS stride
    __shared__ __align__(16) u16 As[128 * LDA];
    __shared__ __align__(16) u16 Bs[128 * LDA];

    const int tid  = threadIdx.x;
    const int wave = tid >> 6, lane = tid & 63;
    const int q = lane >> 4, l15 = lane & 15;
    const int wm = wave >> 1, wn = wave & 1;

    // XCD-aware decode (MB rows must be %8==0; 392 ok)
    const int bid  = blockIdx.x;
    const int xcd  = bid & 7;
    const int t    = bid >> 3;
    const int colb = t % NB;
    const int rowb = xcd + ((t / NB) << 3);
    const int m0 = rowb << 7, n0 = colb << 7;

    f32x4 acc[4][4] = {};

    const int ar = tid >> 2;
    const int ac = (tid & 3) << 3;
    const u16* Ag = A  + (size_t)(m0 + ar) * K + ac;
    const u16* Bg = Bt + (size_t)(n0 + ar) * K + ac;
    const size_t rstep = (size_t)64 * K;

    u32x4 ra0 = *(const u32x4*)Ag;
    u32x4 ra1 = *(const u32x4*)(Ag + rstep);
    u32x4 rb0 = *(const u32x4*)Bg;
    u32x4 rb1 = *(const u32x4*)(Bg + rstep);

    const int KT = K >> 5;
    for (int kt = 0; kt < KT; ++kt) {
        __syncthreads();
        *(u32x4*)&As[ar * LDA + ac]        = ra0;
        *(u32x4*)&As[(ar + 64) * LDA + ac] = ra1;
        *(u32x4*)&Bs[ar * LDA + ac]        = rb0;
        *(u32x4*)&Bs[(ar + 64) * LDA + ac] = rb1;
        if (kt + 1 < KT) {
            const u16* Ag2 = Ag + (kt + 1) * 32;
            const u16* Bg2 = Bg + (kt + 1) * 32;
            ra0 = *(const u32x4*)Ag2;
            ra1 = *(const u32x4*)(Ag2 + rstep);
            rb0 = *(const u32x4*)Bg2;
            rb1 = *(const u32x4*)(Bg2 + rstep);
        }
        __syncthreads();
        bf16x8 af[4], bfv[4];
        #pragma unroll
        for (int i = 0; i < 4; ++i)
            af[i] = *(const bf16x8*)&As[(wm * 64 + i * 16 + l15) * LDA + q * 8];
        #pragma unroll
        for (int j = 0; j < 4; ++j)
            bfv[j] = *(const bf16x8*)&Bs[(wn * 64 + j * 16 + l15) * LDA + q * 8];
        #pragma unroll
        for (int i = 0; i < 4; ++i)
            #pragma unroll
            for (int j = 0; j < 4; ++j)
                acc[i][j] = mfma16(af[i], bfv[j], acc[i][j]);
    }

    // epilogue: row = m0+wm*64+i*16+q*4+r, col = n0+wn*64+j*16+l15
    #pragma unroll
    for (int i = 0; i < 4; ++i) {
        #pragma unroll
        for (int r = 0; r < 4; ++r) {
            const int m = m0 + wm * 64 + i * 16 + q * 4 + r;
            size_t dstrow = 0;
            if (MODE == 1) {
                int bw = m / 49, nt = m - bw * 49;
                int b = bw >> 6, widx = bw & 63;
                int wh = widx >> 3, ww2 = widx & 7;
                int ti = nt / 7, tj = nt - ti * 7;
                int hh = wh * 7 + ti + 3;  if (hh >= 56) hh -= 56;  // roll(+3)
                int wp = ww2 * 7 + tj + 3; if (wp >= 56) wp -= 56;
                dstrow = ((size_t)b * 3136 + hh * 56 + wp) << 8;
            }
            #pragma unroll
            for (int j = 0; j < 4; ++j) {
                const int col = n0 + wn * 64 + j * 16 + l15;
                float v = acc[i][j][r] + bias[col];
                if (MODE == 0) {
                    ((u16*)Cout)[(size_t)m * N + col] = f2b(v);
                } else if (MODE == 2) {
                    // tanh-form gelu: x*(1 - 1/(1+e^{2y})), y = a(x+bx^3)
                    float y = 0.7978845608028654f * (v + 0.044715f * v * v * v);
                    float tt = __expf(2.0f * y);
                    float rr = __builtin_amdgcn_rcpf(tt + 1.0f);
                    v = v - v * rr;
                    ((u16*)Cout)[(size_t)m * N + col] = f2b(v);
                } else if (MODE == 3) {
                    const size_t o = (size_t)m * N + col;
                    ((float*)Cout)[o] = b2f(((const u16*)resid)[o]) + v;
                } else { // MODE 1: residual x (f32), output x2 bf16
                    const size_t o = dstrow + col;
                    ((u16*)Cout)[o] = f2b(((const float*)resid)[o] + v);
                }
            }
        }
    }
}

// =====================================================================
// Attention: 1 wave per (window, head). head_dim=32 == one MFMA K-step.
// =====================================================================
__global__ __launch_bounds__(64)
void attn_kernel(const u16* __restrict__ qkv, const float* __restrict__ bm,
                 u16* __restrict__ out)
{
    constexpr int LDP = 72;   // padded stride (16B-aligned: 72*2=144)
    __shared__ __align__(16) u16 Pl[64 * LDP];
    __shared__ __align__(16) u16 Vt[32 * LDP];

    const int bw   = blockIdx.x >> 3;
    const int h    = blockIdx.x & 7;
    const int widx = bw & 63;
    const int lane = threadIdx.x;
    const int q = lane >> 4, l15 = lane & 15;

    const u16* base = qkv + (size_t)bw * 49 * 768 + h * 32;

    // stage V^T (keys >= 49 zeroed)
    {
        const int key = lane;
        const u16* vp = base + 512 + (size_t)(key < 49 ? key : 0) * 768;
        __align__(16) u16 tmp[32];
        #pragma unroll
        for (int c = 0; c < 4; ++c)
            *(u32x4*)&tmp[c * 8] = *(const u32x4*)(vp + c * 8);
        #pragma unroll
        for (int d = 0; d < 32; ++d)
            Vt[d * LDP + key] = (key < 49) ? tmp[d] : (u16)0;
    }

    // Q K^T
    bf16x8 aq[4], bk[4];
    #pragma unroll
    for (int i = 0; i < 4; ++i) {
        int row = i * 16 + l15; row = (row < 49) ? row : 0;
        aq[i] = *(const bf16x8*)(base + (size_t)row * 768 + q * 8);
    }
    #pragma unroll
    for (int j = 0; j < 4; ++j) {
        int key = j * 16 + l15; key = (key < 49) ? key : 0;
        bk[j] = *(const bf16x8*)(base + (size_t)key * 768 + 256 + q * 8);
    }
    f32x4 s[4][4];
    #pragma unroll
    for (int i = 0; i < 4; ++i)
        #pragma unroll
        for (int j = 0; j < 4; ++j) {
            f32x4 z = {0.f, 0.f, 0.f, 0.f};
            s[i][j] = mfma16(aq[i], bk[j], z);
        }

    // scale + (rel bias + mask) from padded table
    const float* bmb = bm + ((size_t)(widx * 8 + h) << 12);
    #pragma unroll
    for (int i = 0; i < 4; ++i) {
        #pragma unroll
        for (int r = 0; r < 4; ++r) {
            const int n = i * 16 + q * 4 + r;
            const float* rowp = bmb + (n << 6) + l15;
            #pragma unroll
            for (int j = 0; j < 4; ++j)
                s[i][j][r] = fmaf(s[i][j][r], SCALE_F, rowp[j * 16]);
        }
    }

    // softmax per row; write P (bf16) to LDS in row-major A-layout
    #pragma unroll
    for (int i = 0; i < 4; ++i) {
        #pragma unroll
        for (int r = 0; r < 4; ++r) {
            float mx = fmaxf(fmaxf(s[i][0][r], s[i][1][r]), fmaxf(s[i][2][r], s[i][3][r]));
            #pragma unroll
            for (int k = 1; k < 16; k <<= 1) mx = fmaxf(mx, __shfl_xor(mx, k));
            float p[4], sum = 0.f;
            #pragma unroll
            for (int j = 0; j < 4; ++j) { p[j] = __expf(s[i][j][r] - mx); sum += p[j]; }
            #pragma unroll
            for (int k = 1; k < 16; k <<= 1) sum += __shfl_xor(sum, k);
            const float inv = 1.0f / sum;
            const int n = i * 16 + q * 4 + r;
            #pragma unroll
            for (int j = 0; j < 4; ++j)
                Pl[n * LDP + j * 16 + l15] = f2b(p[j] * inv);
        }
    }
    __syncthreads();

    // O = P V
    f32x4 o[4][2] = {};
    #pragma unroll
    for (int ks = 0; ks < 2; ++ks) {
        bf16x8 ap[4], bv[2];
        #pragma unroll
        for (int i = 0; i < 4; ++i)
            ap[i] = *(const bf16x8*)&Pl[(i * 16 + l15) * LDP + ks * 32 + q * 8];
        #pragma unroll
        for (int jd = 0; jd < 2; ++jd)
            bv[jd] = *(const bf16x8*)&Vt[(jd * 16 + l15) * LDP + ks * 32 + q * 8];
        #pragma unroll
        for (int i = 0; i < 4; ++i)
            #pragma unroll
            for (int jd = 0; jd < 2; ++jd)
                o[i][jd] = mfma16(ap[i], bv[jd], o[i][jd]);
    }

    #pragma unroll
    for (int i = 0; i < 4; ++i) {
        #pragma unroll
        for (int r = 0; r < 4; ++r) {
            const int n = i * 16 + q * 4 + r;
            if (n < 49) {
                u16* op = out + ((size_t)(bw * 49 + n) << 8) + h * 32;
                #pragma unroll
                for (int jd = 0; jd < 2; ++jd)
                    op[jd * 16 + l15] = f2b(o[i][jd][r]);
            }
        }
    }
}

// =====================================================================
extern "C" void kernel_launch(void* const* d_in, const int* in_sizes, int n_in,
                              void* d_out, int out_size, void* d_ws, size_t ws_size,
                              hipStream_t stream) {
    const float* x      = (const float*)d_in[0];
    const float* w_qkv  = (const float*)d_in[1];
    const float* b_qkv  = (const float*)d_in[2];
    const float* rel_b  = (const float*)d_in[3];
    const float* w_proj = (const float*)d_in[4];
    const float* b_proj = (const float*)d_in[5];
    const float* g1     = (const float*)d_in[6];
    const float* be1    = (const float*)d_in[7];
    const float* g2     = (const float*)d_in[8];
    const float* be2    = (const float*)d_in[9];
    const float* w_fc1  = (const float*)d_in[10];
    const float* b_fc1  = (const float*)d_in[11];
    const float* w_fc2  = (const float*)d_in[12];
    const float* b_fc2  = (const float*)d_in[13];
    const float* amask  = (const float*)d_in[14];

    char* ws = (char*)d_ws;
    u16*   xw     = (u16*)(ws);                 // 50176*256 bf16 = 25,690,112
    u16*   qkvb   = (u16*)(ws + 25690112);      // 50176*768 bf16 = 77,070,336
    u16*   attno  = (u16*)(ws + 102760448);     // 50176*256 bf16 = 25,690,112
    u16*   x2b    = (u16*)(ws + 128450560);     // 50176*256 bf16 = 25,690,112
    u16*   wqkvT  = (u16*)(ws + 154140672);     // 393,216
    u16*   wprojT = (u16*)(ws + 154533888);     // 131,072
    u16*   wfc1T  = (u16*)(ws + 154664960);     // 524,288
    u16*   wfc2T  = (u16*)(ws + 155189248);     // 524,288
    float* bm     = (float*)(ws + 155713536);   // 64*8*64*64 f32 = 8,388,608
    u16*   h1     = qkvb;                       // fc1 out reuses qkv+attno region

    prep_kernel<<<12288, 256, 0, stream>>>(w_qkv, w_proj, w_fc1, w_fc2, rel_b, amask,
                                           wqkvT, wprojT, wfc1T, wfc2T, bm);
    ln_kernel<<<12544, 256, 0, stream>>>(x, nullptr, g1, be1, xw, 0);
    gemm128<0><<<392 * 6, 256, 0, stream>>>(xw, wqkvT, b_qkv, qkvb, 768, 256, nullptr, 6);
    attn_kernel<<<8192, 64, 0, stream>>>(qkvb, bm, attno);
    gemm128<1><<<392 * 2, 256, 0, stream>>>(attno, wprojT, b_proj, x2b, 256, 256, x, 2);
    ln_kernel<<<12544, 256, 0, stream>>>(nullptr, x2b, g2, be2, xw, 2);
    gemm128<2><<<392 * 8, 256, 0, stream>>>(xw, wfc1T, b_fc1, h1, 1024, 256, nullptr, 8);
    gemm128<3><<<392 * 2, 256, 0, stream>>>(h1, wfc2T, b_fc2, (float*)d_out, 256, 1024, x2b, 2);
}